// Round 6
// baseline (498.590 us; speedup 1.0000x reference)
//
#include <hip/hip_runtime.h>
#include <hip/hip_bf16.h>

#define N_NODES   50000
#define N_EDGES   500000
#define FDIM      128
#define N_CLASSES 32
#define N_GRAPHS  64

// ---------------------------------------------------------------------------
// Preprocessing: degree count, rsqrt, prefix scan, CSR fill
// ---------------------------------------------------------------------------

__global__ void deg_kernel(const int* __restrict__ dst, int* __restrict__ deg, int E) {
    int e = blockIdx.x * blockDim.x + threadIdx.x;
    if (e < E) atomicAdd(&deg[dst[e]], 1);
}

__global__ void dis_kernel(const int* __restrict__ deg, float* __restrict__ dis, int n) {
    int v = blockIdx.x * blockDim.x + threadIdx.x;
    if (v < n) dis[v] = rsqrtf((float)deg[v] + 1.0f);
}

__global__ void scan_partial(const int* __restrict__ deg, int* __restrict__ part, int n) {
    __shared__ int s[512];
    int t = threadIdx.x;
    int i = blockIdx.x * 512 + t;
    s[t] = (i < n) ? deg[i] : 0;
    __syncthreads();
    for (int o = 256; o > 0; o >>= 1) {
        if (t < o) s[t] += s[t + o];
        __syncthreads();
    }
    if (t == 0) part[blockIdx.x] = s[0];
}

__global__ void scan_offsets(int* part, int nb) {
    if (blockIdx.x == 0 && threadIdx.x == 0) {
        int acc = 0;
        for (int i = 0; i < nb; i++) { int v = part[i]; part[i] = acc; acc += v; }
    }
}

__global__ void scan_final(const int* __restrict__ deg, const int* __restrict__ part,
                           int* __restrict__ rowptr, int n) {
    __shared__ int s[512];
    int t = threadIdx.x;
    int i = blockIdx.x * 512 + t;
    int v = (i < n) ? deg[i] : 0;
    s[t] = v;
    __syncthreads();
    for (int o = 1; o < 512; o <<= 1) {
        int x = (t >= o) ? s[t - o] : 0;
        __syncthreads();
        s[t] += x;
        __syncthreads();
    }
    if (i < n) rowptr[i] = part[blockIdx.x] + s[t] - v;   // exclusive
}

__global__ void fill_csr(const int* __restrict__ src, const int* __restrict__ dst,
                         const int* __restrict__ rowptr, int* __restrict__ fill,
                         const float* __restrict__ dis,
                         int2* __restrict__ csr_sw, int E) {
    int e = blockIdx.x * blockDim.x + threadIdx.x;
    if (e >= E) return;
    int d = dst[e], s = src[e];
    int pos = rowptr[d] + atomicAdd(&fill[d], 1);
    float w = dis[s] * dis[d];
    csr_sw[pos] = make_int2(s, __float_as_int(w));
}

// ---------------------------------------------------------------------------
// GEMM: H[n][128] = X[n][128] @ W[128][128]
// 32x128 tile, 256 threads, 2x8 micro-tile -> 1563 blocks (~24 waves/CU)
// ---------------------------------------------------------------------------

__global__ __launch_bounds__(256) void gemm32(const float* __restrict__ X,
                                              const float* __restrict__ W,
                                              float* __restrict__ H, int n) {
    __shared__ __align__(16) float xs[32][36];   // xs[k][row], stride 36 keeps f2 aligned
    __shared__ __align__(16) float ws[32][132];  // ws[k][col]
    int t = threadIdx.x;
    int ti = t & 15;     // row pair index: rows ti*2, ti*2+1
    int tj = t >> 4;     // col group: cols tj*4..+3 and tj*4+64..+67
    int rowBase = blockIdx.x * 32;

    float acc[2][8];
#pragma unroll
    for (int r = 0; r < 2; r++)
#pragma unroll
        for (int c = 0; c < 8; c++) acc[r][c] = 0.f;

    for (int k0 = 0; k0 < 128; k0 += 32) {
        __syncthreads();
        // stage X transposed: one float4 per thread
        {
            int r = t >> 3, kq = t & 7;
            int grow = rowBase + r;
            float4 v = make_float4(0.f, 0.f, 0.f, 0.f);
            if (grow < n) v = *(const float4*)(X + (size_t)grow * FDIM + k0 + kq * 4);
            xs[kq * 4 + 0][r] = v.x;
            xs[kq * 4 + 1][r] = v.y;
            xs[kq * 4 + 2][r] = v.z;
            xs[kq * 4 + 3][r] = v.w;
        }
        // stage W natural layout: 4 float4 per thread
        {
            int c4 = t & 31, kr = t >> 5;
#pragma unroll
            for (int p = 0; p < 4; p++) {
                int k = kr + 8 * p;
                float4 v = *(const float4*)(W + (size_t)(k0 + k) * FDIM + c4 * 4);
                *(float4*)&ws[k][c4 * 4] = v;
            }
        }
        __syncthreads();
#pragma unroll 8
        for (int k = 0; k < 32; k++) {
            float2 a = *(const float2*)&xs[k][ti * 2];
            float4 b0 = *(const float4*)&ws[k][tj * 4];
            float4 b1 = *(const float4*)&ws[k][tj * 4 + 64];
            float br[8] = {b0.x, b0.y, b0.z, b0.w, b1.x, b1.y, b1.z, b1.w};
#pragma unroll
            for (int c = 0; c < 8; c++) {
                acc[0][c] = fmaf(a.x, br[c], acc[0][c]);
                acc[1][c] = fmaf(a.y, br[c], acc[1][c]);
            }
        }
    }

#pragma unroll
    for (int rr = 0; rr < 2; rr++) {
        int grow = rowBase + ti * 2 + rr;
        if (grow < n) {
            float4 o0 = {acc[rr][0], acc[rr][1], acc[rr][2], acc[rr][3]};
            float4 o1 = {acc[rr][4], acc[rr][5], acc[rr][6], acc[rr][7]};
            *(float4*)(H + (size_t)grow * FDIM + tj * 4) = o0;
            *(float4*)(H + (size_t)grow * FDIM + tj * 4 + 64) = o1;
        }
    }
}

// ---------------------------------------------------------------------------
// Aggregate: OUT[v] = sum_e w_e * H[src_e] + (1/deg) * H[v] + b, optional ReLU
// One wave per TWO nodes; gathers of both nodes batched jointly so up to 16
// independent loads are in flight (breaks the latency chain harder than R2).
// ---------------------------------------------------------------------------

#define GATH4(SW, E0, AX, AY)                                                  \
    {                                                                          \
        int2 q0 = SW[E0], q1 = SW[E0 + 1], q2 = SW[E0 + 2], q3 = SW[E0 + 3];   \
        float2 n0 = *(const float2*)(H + (size_t)q0.x * FDIM + lane * 2);      \
        float2 n1 = *(const float2*)(H + (size_t)q1.x * FDIM + lane * 2);      \
        float2 n2 = *(const float2*)(H + (size_t)q2.x * FDIM + lane * 2);      \
        float2 n3 = *(const float2*)(H + (size_t)q3.x * FDIM + lane * 2);      \
        AX = fmaf(__int_as_float(q0.y), n0.x, AX);                             \
        AY = fmaf(__int_as_float(q0.y), n0.y, AY);                             \
        AX = fmaf(__int_as_float(q1.y), n1.x, AX);                             \
        AY = fmaf(__int_as_float(q1.y), n1.y, AY);                             \
        AX = fmaf(__int_as_float(q2.y), n2.x, AX);                             \
        AY = fmaf(__int_as_float(q2.y), n2.y, AY);                             \
        AX = fmaf(__int_as_float(q3.y), n3.x, AX);                             \
        AY = fmaf(__int_as_float(q3.y), n3.y, AY);                             \
    }

__device__ __forceinline__ void drain_edges(const float* __restrict__ H,
                                            const int2* __restrict__ sw, int cnt,
                                            int& e, int lane, float& ax, float& ay) {
    for (; e + 8 <= cnt; e += 8) {
        GATH4(sw, e, ax, ay);
        GATH4(sw, e + 4, ax, ay);
    }
    for (; e + 4 <= cnt; e += 4) GATH4(sw, e, ax, ay);
    for (; e < cnt; e++) {
        int2 p = sw[e];
        float2 m = *(const float2*)(H + (size_t)p.x * FDIM + lane * 2);
        ax = fmaf(__int_as_float(p.y), m.x, ax);
        ay = fmaf(__int_as_float(p.y), m.y, ay);
    }
}

__global__ __launch_bounds__(256) void agg_kernel(const float* __restrict__ H,
                                                  float* __restrict__ OUT,
                                                  const int* __restrict__ rowptr,
                                                  const int* __restrict__ degi,
                                                  const int2* __restrict__ csr_sw,
                                                  const float* __restrict__ dis,
                                                  const float* __restrict__ bias,
                                                  int n, int relu) {
    int wid = (blockIdx.x * blockDim.x + threadIdx.x) >> 6;
    int lane = threadIdx.x & 63;
    int v0 = wid * 2;
    if (v0 >= n) return;
    int v1 = v0 + 1;  // N is even; v1 always valid

    const int2* sw0 = csr_sw + rowptr[v0];
    const int2* sw1 = csr_sw + rowptr[v1];
    int c0 = degi[v0], c1 = degi[v1];
    float a0x = 0.f, a0y = 0.f, a1x = 0.f, a1y = 0.f;
    int e0 = 0, e1 = 0;

    // joint batches: 16 gathers in flight
    while (e0 + 8 <= c0 && e1 + 8 <= c1) {
        GATH4(sw0, e0, a0x, a0y);
        GATH4(sw0, e0 + 4, a0x, a0y);
        GATH4(sw1, e1, a1x, a1y);
        GATH4(sw1, e1 + 4, a1x, a1y);
        e0 += 8; e1 += 8;
    }
    while (e0 + 4 <= c0 && e1 + 4 <= c1) {
        GATH4(sw0, e0, a0x, a0y);
        GATH4(sw1, e1, a1x, a1y);
        e0 += 4; e1 += 4;
    }
    drain_edges(H, sw0, c0, e0, lane, a0x, a0y);
    drain_edges(H, sw1, c1, e1, lane, a1x, a1y);

    float2 bb = *(const float2*)(bias + lane * 2);
    {
        float dv = dis[v0];
        float ns = dv * dv;
        float2 hv = *(const float2*)(H + (size_t)v0 * FDIM + lane * 2);
        float ox = a0x + ns * hv.x + bb.x;
        float oy = a0y + ns * hv.y + bb.y;
        if (relu) { ox = fmaxf(ox, 0.f); oy = fmaxf(oy, 0.f); }
        *(float2*)(OUT + (size_t)v0 * FDIM + lane * 2) = make_float2(ox, oy);
    }
    {
        float dv = dis[v1];
        float ns = dv * dv;
        float2 hv = *(const float2*)(H + (size_t)v1 * FDIM + lane * 2);
        float ox = a1x + ns * hv.x + bb.x;
        float oy = a1y + ns * hv.y + bb.y;
        if (relu) { ox = fmaxf(ox, 0.f); oy = fmaxf(oy, 0.f); }
        *(float2*)(OUT + (size_t)v1 * FDIM + lane * 2) = make_float2(ox, oy);
    }
}

// ---------------------------------------------------------------------------
// Pooling: batch[] is SORTED. Each 128-thread block owns a contiguous node
// chunk; thread t owns feature t; flush one atomic per graph-boundary.
// ---------------------------------------------------------------------------

#define POOL_BLOCKS 1024

__global__ __launch_bounds__(128) void pool_kernel(const float* __restrict__ H,
                                                   const int* __restrict__ batch,
                                                   float* __restrict__ psum,
                                                   float* __restrict__ pcnt, int n) {
    int t = threadIdx.x;  // feature index 0..127
    int chunk = (n + POOL_BLOCKS - 1) / POOL_BLOCKS;
    int lo = blockIdx.x * chunk;
    int hi = lo + chunk; if (hi > n) hi = n;
    if (lo >= hi) return;

    float acc = 0.f;
    int cnt = 0;
    int curg = batch[lo];
    float hv = H[(size_t)lo * FDIM + t];
    int g = curg;
    for (int v = lo; v < hi; v++) {
        float hcur = hv;
        int gcur = g;
        if (v + 1 < hi) {
            hv = H[(size_t)(v + 1) * FDIM + t];
            g = batch[v + 1];
        }
        if (gcur != curg) {
            atomicAdd(&psum[curg * FDIM + t], acc);
            if (t == 0) atomicAdd(&pcnt[curg], (float)cnt);
            acc = 0.f; cnt = 0; curg = gcur;
        }
        acc += hcur;
        cnt++;
    }
    atomicAdd(&psum[curg * FDIM + t], acc);
    if (t == 0) atomicAdd(&pcnt[curg], (float)cnt);
}

__global__ void final_lin(const float* __restrict__ psum, const float* __restrict__ pcnt,
                          const float* __restrict__ Wl, const float* __restrict__ bl,
                          float* __restrict__ out) {
    int t = blockIdx.x * blockDim.x + threadIdx.x;
    if (t >= N_GRAPHS * N_CLASSES) return;
    int g = t >> 5, c = t & 31;
    float inv = 1.0f / fmaxf(pcnt[g], 1.0f);
    float s = 0.f;
    for (int k = 0; k < FDIM; k++) s = fmaf(psum[g * FDIM + k], Wl[k * N_CLASSES + c], s);
    out[t] = s * inv + bl[c];
}

// ---------------------------------------------------------------------------

static inline size_t align256(size_t x) { return (x + 255) & ~(size_t)255; }

extern "C" void kernel_launch(void* const* d_in, const int* in_sizes, int n_in,
                              void* d_out, int out_size, void* d_ws, size_t ws_size,
                              hipStream_t stream) {
    const float* x     = (const float*)d_in[0];
    const int*   ei    = (const int*)d_in[1];
    const int*   batch = (const int*)d_in[2];
    const float* Wls[5] = {(const float*)d_in[3], (const float*)d_in[5], (const float*)d_in[7],
                           (const float*)d_in[9], (const float*)d_in[11]};
    const float* bls[5] = {(const float*)d_in[4], (const float*)d_in[6], (const float*)d_in[8],
                           (const float*)d_in[10], (const float*)d_in[12]};
    const float* W_lin = (const float*)d_in[13];
    const float* b_lin = (const float*)d_in[14];
    float* out = (float*)d_out;

    const int N = N_NODES, E = N_EDGES;
    const int* src = ei;
    const int* dst = ei + E;

    // workspace layout
    char* p = (char*)d_ws;
    size_t off = 0;
    float* hA = (float*)(p + off); off = align256(off + (size_t)N * FDIM * 4);
    float* hB = (float*)(p + off); off = align256(off + (size_t)N * FDIM * 4);
    int*   deg = (int*)(p + off); off = align256(off + (size_t)N * 4);
    float* dis = (float*)(p + off); off = align256(off + (size_t)N * 4);
    int*   rowptr = (int*)(p + off); off = align256(off + (size_t)N * 4);
    int*   fill = (int*)(p + off); off = align256(off + (size_t)N * 4);
    int*   part = (int*)(p + off); off = align256(off + 512);
    int2*  csr_sw = (int2*)(p + off); off = align256(off + (size_t)E * 8);
    float* psum = (float*)(p + off); off = align256(off + (size_t)N_GRAPHS * FDIM * 4);
    float* pcnt = (float*)(p + off); off = align256(off + (size_t)N_GRAPHS * 4);
    (void)ws_size; (void)n_in; (void)in_sizes; (void)out_size;

    // zero accumulators
    hipMemsetAsync(deg, 0, (size_t)N * 4, stream);
    hipMemsetAsync(fill, 0, (size_t)N * 4, stream);
    hipMemsetAsync(psum, 0, (size_t)N_GRAPHS * FDIM * 4, stream);
    hipMemsetAsync(pcnt, 0, (size_t)N_GRAPHS * 4, stream);

    // preprocessing
    deg_kernel<<<(E + 255) / 256, 256, 0, stream>>>(dst, deg, E);
    dis_kernel<<<(N + 255) / 256, 256, 0, stream>>>(deg, dis, N);
    int nChunks = (N + 511) / 512;  // 98
    scan_partial<<<nChunks, 512, 0, stream>>>(deg, part, N);
    scan_offsets<<<1, 64, 0, stream>>>(part, nChunks);
    scan_final<<<nChunks, 512, 0, stream>>>(deg, part, rowptr, N);
    fill_csr<<<(E + 255) / 256, 256, 0, stream>>>(src, dst, rowptr, fill, dis,
                                                  csr_sw, E);

    // 5 GCN layers, ping-pong hA/hB
    int gemmBlocks = (N + 31) / 32;               // 1563
    int aggBlocks = ((N / 2) * 64 + 255) / 256;   // 6250
    const float* cur = x;
    for (int l = 0; l < 5; l++) {
        gemm32<<<gemmBlocks, 256, 0, stream>>>(cur, Wls[l], hA, N);
        int relu = (l < 4) ? 1 : 0;
        agg_kernel<<<aggBlocks, 256, 0, stream>>>(hA, hB, rowptr, deg, csr_sw,
                                                  dis, bls[l], N, relu);
        cur = hB;
    }

    // pooling + classifier
    pool_kernel<<<POOL_BLOCKS, 128, 0, stream>>>(hB, batch, psum, pcnt, N);
    final_lin<<<(N_GRAPHS * N_CLASSES + 255) / 256, 256, 0, stream>>>(psum, pcnt, W_lin,
                                                                      b_lin, out);
}

// Round 7
// 448.858 us; speedup vs baseline: 1.1108x; 1.1108x over previous
//
#include <hip/hip_runtime.h>
#include <hip/hip_bf16.h>

#define N_NODES   50000
#define N_EDGES   500000
#define FDIM      128
#define N_CLASSES 32
#define N_GRAPHS  64

// ---------------------------------------------------------------------------
// Preprocessing: degree count, prefix scan (fused rsqrt), CSR fill
// ---------------------------------------------------------------------------

__global__ void deg_kernel(const int* __restrict__ dst, int* __restrict__ deg, int E) {
    int e = blockIdx.x * blockDim.x + threadIdx.x;
    if (e < E) atomicAdd(&deg[dst[e]], 1);
}

// scan_partial also computes dis[] (fused: saves one launch)
__global__ void scan_partial(const int* __restrict__ deg, int* __restrict__ part,
                             float* __restrict__ dis, int n) {
    __shared__ int s[512];
    int t = threadIdx.x;
    int i = blockIdx.x * 512 + t;
    int d = (i < n) ? deg[i] : 0;
    if (i < n) dis[i] = rsqrtf((float)d + 1.0f);
    s[t] = d;
    __syncthreads();
    for (int o = 256; o > 0; o >>= 1) {
        if (t < o) s[t] += s[t + o];
        __syncthreads();
    }
    if (t == 0) part[blockIdx.x] = s[0];
}

__global__ void scan_offsets(int* part, int nb) {
    if (blockIdx.x == 0 && threadIdx.x == 0) {
        int acc = 0;
        for (int i = 0; i < nb; i++) { int v = part[i]; part[i] = acc; acc += v; }
    }
}

__global__ void scan_final(const int* __restrict__ deg, const int* __restrict__ part,
                           int* __restrict__ rowptr, int n) {
    __shared__ int s[512];
    int t = threadIdx.x;
    int i = blockIdx.x * 512 + t;
    int v = (i < n) ? deg[i] : 0;
    s[t] = v;
    __syncthreads();
    for (int o = 1; o < 512; o <<= 1) {
        int x = (t >= o) ? s[t - o] : 0;
        __syncthreads();
        s[t] += x;
        __syncthreads();
    }
    if (i < n) rowptr[i] = part[blockIdx.x] + s[t] - v;   // exclusive
}

__global__ void fill_csr(const int* __restrict__ src, const int* __restrict__ dst,
                         const int* __restrict__ rowptr, int* __restrict__ fill,
                         const float* __restrict__ dis,
                         int2* __restrict__ csr_sw, int E) {
    int e = blockIdx.x * blockDim.x + threadIdx.x;
    if (e >= E) return;
    int d = dst[e], s = src[e];
    int pos = rowptr[d] + atomicAdd(&fill[d], 1);
    float w = dis[s] * dis[d];
    csr_sw[pos] = make_int2(s, __float_as_int(w));
}

// ---------------------------------------------------------------------------
// GEMM: H[n][128] = X[n][128] @ W[128][128]
// 32x128 tile, 256 threads, 4x4 micro-tile (32B LDS / 16 FMA = 2.0 B/FMA)
// 1563 blocks -> ~6 blocks/CU, ~24 waves/CU
// ---------------------------------------------------------------------------

__global__ __launch_bounds__(256) void gemm32(const float* __restrict__ X,
                                              const float* __restrict__ W,
                                              float* __restrict__ H, int n) {
    __shared__ __align__(16) float xs[32][36];   // xs[k][row]; 36*4=144B row stride (16B-mult)
    __shared__ __align__(16) float ws[32][132];  // ws[k][col]; 132*4=528B row stride (16B-mult)
    int t = threadIdx.x;
    int ti = t & 7;      // row group: rows ti*4 .. ti*4+3
    int tj = t >> 3;     // col group: cols tj*4 .. tj*4+3
    int rowBase = blockIdx.x * 32;

    float acc[4][4];
#pragma unroll
    for (int r = 0; r < 4; r++)
#pragma unroll
        for (int c = 0; c < 4; c++) acc[r][c] = 0.f;

    for (int k0 = 0; k0 < 128; k0 += 32) {
        __syncthreads();
        // stage X transposed: one float4 per thread
        {
            int r = t >> 3, kq = t & 7;
            int grow = rowBase + r;
            float4 v = make_float4(0.f, 0.f, 0.f, 0.f);
            if (grow < n) v = *(const float4*)(X + (size_t)grow * FDIM + k0 + kq * 4);
            xs[kq * 4 + 0][r] = v.x;
            xs[kq * 4 + 1][r] = v.y;
            xs[kq * 4 + 2][r] = v.z;
            xs[kq * 4 + 3][r] = v.w;
        }
        // stage W natural layout: 4 float4 per thread
        {
            int c4 = t & 31, kr = t >> 5;
#pragma unroll
            for (int p = 0; p < 4; p++) {
                int k = kr + 8 * p;
                float4 v = *(const float4*)(W + (size_t)(k0 + k) * FDIM + c4 * 4);
                *(float4*)&ws[k][c4 * 4] = v;
            }
        }
        __syncthreads();
#pragma unroll 8
        for (int k = 0; k < 32; k++) {
            float4 a = *(const float4*)&xs[k][ti * 4];
            float4 b = *(const float4*)&ws[k][tj * 4];
            float ar[4] = {a.x, a.y, a.z, a.w};
            float br[4] = {b.x, b.y, b.z, b.w};
#pragma unroll
            for (int r = 0; r < 4; r++)
#pragma unroll
                for (int c = 0; c < 4; c++) acc[r][c] = fmaf(ar[r], br[c], acc[r][c]);
        }
    }

#pragma unroll
    for (int rr = 0; rr < 4; rr++) {
        int grow = rowBase + ti * 4 + rr;
        if (grow < n) {
            float4 o = {acc[rr][0], acc[rr][1], acc[rr][2], acc[rr][3]};
            *(float4*)(H + (size_t)grow * FDIM + tj * 4) = o;
        }
    }
}

// ---------------------------------------------------------------------------
// Aggregate (R2-proven): OUT[v] = sum_e w_e*H[src_e] + (1/deg)*H[v] + b (+ReLU)
// One wave per node, 2 floats/lane, 8/4/1-deep unrolled gathers.
// ---------------------------------------------------------------------------

__global__ __launch_bounds__(256) void agg_kernel(const float* __restrict__ H,
                                                  float* __restrict__ OUT,
                                                  const int* __restrict__ rowptr,
                                                  const int* __restrict__ degi,
                                                  const int2* __restrict__ csr_sw,
                                                  const float* __restrict__ dis,
                                                  const float* __restrict__ bias,
                                                  int n, int relu) {
    int wid = (blockIdx.x * blockDim.x + threadIdx.x) >> 6;
    int lane = threadIdx.x & 63;
    if (wid >= n) return;
    int v = wid;
    const int2* sw = csr_sw + rowptr[v];
    int cnt = degi[v];
    float ax = 0.f, ay = 0.f;
    int e = 0;

    for (; e + 8 <= cnt; e += 8) {
        int2 p0 = sw[e + 0], p1 = sw[e + 1], p2 = sw[e + 2], p3 = sw[e + 3];
        int2 p4 = sw[e + 4], p5 = sw[e + 5], p6 = sw[e + 6], p7 = sw[e + 7];
        float2 m0 = *(const float2*)(H + (size_t)p0.x * FDIM + lane * 2);
        float2 m1 = *(const float2*)(H + (size_t)p1.x * FDIM + lane * 2);
        float2 m2 = *(const float2*)(H + (size_t)p2.x * FDIM + lane * 2);
        float2 m3 = *(const float2*)(H + (size_t)p3.x * FDIM + lane * 2);
        float2 m4 = *(const float2*)(H + (size_t)p4.x * FDIM + lane * 2);
        float2 m5 = *(const float2*)(H + (size_t)p5.x * FDIM + lane * 2);
        float2 m6 = *(const float2*)(H + (size_t)p6.x * FDIM + lane * 2);
        float2 m7 = *(const float2*)(H + (size_t)p7.x * FDIM + lane * 2);
        ax = fmaf(__int_as_float(p0.y), m0.x, ax); ay = fmaf(__int_as_float(p0.y), m0.y, ay);
        ax = fmaf(__int_as_float(p1.y), m1.x, ax); ay = fmaf(__int_as_float(p1.y), m1.y, ay);
        ax = fmaf(__int_as_float(p2.y), m2.x, ax); ay = fmaf(__int_as_float(p2.y), m2.y, ay);
        ax = fmaf(__int_as_float(p3.y), m3.x, ax); ay = fmaf(__int_as_float(p3.y), m3.y, ay);
        ax = fmaf(__int_as_float(p4.y), m4.x, ax); ay = fmaf(__int_as_float(p4.y), m4.y, ay);
        ax = fmaf(__int_as_float(p5.y), m5.x, ax); ay = fmaf(__int_as_float(p5.y), m5.y, ay);
        ax = fmaf(__int_as_float(p6.y), m6.x, ax); ay = fmaf(__int_as_float(p6.y), m6.y, ay);
        ax = fmaf(__int_as_float(p7.y), m7.x, ax); ay = fmaf(__int_as_float(p7.y), m7.y, ay);
    }
    for (; e + 4 <= cnt; e += 4) {
        int2 p0 = sw[e + 0], p1 = sw[e + 1], p2 = sw[e + 2], p3 = sw[e + 3];
        float2 m0 = *(const float2*)(H + (size_t)p0.x * FDIM + lane * 2);
        float2 m1 = *(const float2*)(H + (size_t)p1.x * FDIM + lane * 2);
        float2 m2 = *(const float2*)(H + (size_t)p2.x * FDIM + lane * 2);
        float2 m3 = *(const float2*)(H + (size_t)p3.x * FDIM + lane * 2);
        ax = fmaf(__int_as_float(p0.y), m0.x, ax); ay = fmaf(__int_as_float(p0.y), m0.y, ay);
        ax = fmaf(__int_as_float(p1.y), m1.x, ax); ay = fmaf(__int_as_float(p1.y), m1.y, ay);
        ax = fmaf(__int_as_float(p2.y), m2.x, ax); ay = fmaf(__int_as_float(p2.y), m2.y, ay);
        ax = fmaf(__int_as_float(p3.y), m3.x, ax); ay = fmaf(__int_as_float(p3.y), m3.y, ay);
    }
    for (; e < cnt; e++) {
        int2 p = sw[e];
        float2 m = *(const float2*)(H + (size_t)p.x * FDIM + lane * 2);
        ax = fmaf(__int_as_float(p.y), m.x, ax);
        ay = fmaf(__int_as_float(p.y), m.y, ay);
    }

    float dv = dis[v];
    float ns = dv * dv;
    float2 hv = *(const float2*)(H + (size_t)v * FDIM + lane * 2);
    float2 bb = *(const float2*)(bias + lane * 2);
    float ox = ax + ns * hv.x + bb.x;
    float oy = ay + ns * hv.y + bb.y;
    if (relu) { ox = fmaxf(ox, 0.f); oy = fmaxf(oy, 0.f); }
    *(float2*)(OUT + (size_t)v * FDIM + lane * 2) = make_float2(ox, oy);
}

// ---------------------------------------------------------------------------
// Pooling: batch[] is SORTED. Each 128-thread block owns a contiguous node
// chunk; thread t owns feature t; flush one atomic per graph-boundary.
// ---------------------------------------------------------------------------

#define POOL_BLOCKS 1024

__global__ __launch_bounds__(128) void pool_kernel(const float* __restrict__ H,
                                                   const int* __restrict__ batch,
                                                   float* __restrict__ psum,
                                                   float* __restrict__ pcnt, int n) {
    int t = threadIdx.x;  // feature index 0..127
    int chunk = (n + POOL_BLOCKS - 1) / POOL_BLOCKS;
    int lo = blockIdx.x * chunk;
    int hi = lo + chunk; if (hi > n) hi = n;
    if (lo >= hi) return;

    float acc = 0.f;
    int cnt = 0;
    int curg = batch[lo];
    float hv = H[(size_t)lo * FDIM + t];
    int g = curg;
    for (int v = lo; v < hi; v++) {
        float hcur = hv;
        int gcur = g;
        if (v + 1 < hi) {
            hv = H[(size_t)(v + 1) * FDIM + t];
            g = batch[v + 1];
        }
        if (gcur != curg) {
            atomicAdd(&psum[curg * FDIM + t], acc);
            if (t == 0) atomicAdd(&pcnt[curg], (float)cnt);
            acc = 0.f; cnt = 0; curg = gcur;
        }
        acc += hcur;
        cnt++;
    }
    atomicAdd(&psum[curg * FDIM + t], acc);
    if (t == 0) atomicAdd(&pcnt[curg], (float)cnt);
}

__global__ void final_lin(const float* __restrict__ psum, const float* __restrict__ pcnt,
                          const float* __restrict__ Wl, const float* __restrict__ bl,
                          float* __restrict__ out) {
    int t = blockIdx.x * blockDim.x + threadIdx.x;
    if (t >= N_GRAPHS * N_CLASSES) return;
    int g = t >> 5, c = t & 31;
    float inv = 1.0f / fmaxf(pcnt[g], 1.0f);
    float s = 0.f;
    for (int k = 0; k < FDIM; k++) s = fmaf(psum[g * FDIM + k], Wl[k * N_CLASSES + c], s);
    out[t] = s * inv + bl[c];
}

// ---------------------------------------------------------------------------

static inline size_t align256(size_t x) { return (x + 255) & ~(size_t)255; }

extern "C" void kernel_launch(void* const* d_in, const int* in_sizes, int n_in,
                              void* d_out, int out_size, void* d_ws, size_t ws_size,
                              hipStream_t stream) {
    const float* x     = (const float*)d_in[0];
    const int*   ei    = (const int*)d_in[1];
    const int*   batch = (const int*)d_in[2];
    const float* Wls[5] = {(const float*)d_in[3], (const float*)d_in[5], (const float*)d_in[7],
                           (const float*)d_in[9], (const float*)d_in[11]};
    const float* bls[5] = {(const float*)d_in[4], (const float*)d_in[6], (const float*)d_in[8],
                           (const float*)d_in[10], (const float*)d_in[12]};
    const float* W_lin = (const float*)d_in[13];
    const float* b_lin = (const float*)d_in[14];
    float* out = (float*)d_out;

    const int N = N_NODES, E = N_EDGES;
    const int* src = ei;
    const int* dst = ei + E;

    // workspace layout: zeroed arrays (deg,fill,psum,pcnt) laid out contiguously
    char* p = (char*)d_ws;
    size_t off = 0;
    float* hA = (float*)(p + off); off = align256(off + (size_t)N * FDIM * 4);
    float* hB = (float*)(p + off); off = align256(off + (size_t)N * FDIM * 4);
    int2*  csr_sw = (int2*)(p + off); off = align256(off + (size_t)E * 8);
    float* dis = (float*)(p + off); off = align256(off + (size_t)N * 4);
    int*   rowptr = (int*)(p + off); off = align256(off + (size_t)N * 4);
    int*   part = (int*)(p + off); off = align256(off + 512);
    size_t zero_off = off;
    int*   deg = (int*)(p + off); off = align256(off + (size_t)N * 4);
    int*   fill = (int*)(p + off); off = align256(off + (size_t)N * 4);
    float* psum = (float*)(p + off); off = align256(off + (size_t)N_GRAPHS * FDIM * 4);
    float* pcnt = (float*)(p + off); off = align256(off + (size_t)N_GRAPHS * 4);
    size_t zero_bytes = off - zero_off;
    (void)ws_size; (void)n_in; (void)in_sizes; (void)out_size;

    // single fused zero of all accumulators
    hipMemsetAsync(p + zero_off, 0, zero_bytes, stream);

    // preprocessing
    deg_kernel<<<(E + 255) / 256, 256, 0, stream>>>(dst, deg, E);
    int nChunks = (N + 511) / 512;  // 98
    scan_partial<<<nChunks, 512, 0, stream>>>(deg, part, dis, N);
    scan_offsets<<<1, 64, 0, stream>>>(part, nChunks);
    scan_final<<<nChunks, 512, 0, stream>>>(deg, part, rowptr, N);
    fill_csr<<<(E + 255) / 256, 256, 0, stream>>>(src, dst, rowptr, fill, dis,
                                                  csr_sw, E);

    // 5 GCN layers, ping-pong hA/hB
    int gemmBlocks = (N + 31) / 32;          // 1563
    int aggBlocks = (N * 64 + 255) / 256;    // 12500
    const float* cur = x;
    for (int l = 0; l < 5; l++) {
        gemm32<<<gemmBlocks, 256, 0, stream>>>(cur, Wls[l], hA, N);
        int relu = (l < 4) ? 1 : 0;
        agg_kernel<<<aggBlocks, 256, 0, stream>>>(hA, hB, rowptr, deg, csr_sw,
                                                  dis, bls[l], N, relu);
        cur = hB;
    }

    // pooling + classifier
    pool_kernel<<<POOL_BLOCKS, 128, 0, stream>>>(hB, batch, psum, pcnt, N);
    final_lin<<<(N_GRAPHS * N_CLASSES + 255) / 256, 256, 0, stream>>>(psum, pcnt, W_lin,
                                                                      b_lin, out);
}